// Round 4
// baseline (728.069 us; speedup 1.0000x reference)
//
#include <hip/hip_runtime.h>
#include <hip/hip_bf16.h>
#include <stdint.h>

#define N_DIM 8192
#define H_DIM 1024
#define E_DIM 8192
#define PENALTY_F 10.0f
#define WSCALE 16.0f      // weights and H outputs stored *16 in e4m3
#define INV_WSCALE 0.0625f

typedef unsigned short u16;
typedef unsigned char u8;
typedef unsigned int u32;
typedef __attribute__((ext_vector_type(4))) float f32x4;
typedef __attribute__((ext_vector_type(2))) float f32x2;
typedef __attribute__((ext_vector_type(4))) int i32x4;
typedef __attribute__((ext_vector_type(8))) int i32x8;

// pack 4 floats -> 4 e4m3 bytes (OCP on gfx950)
__device__ __forceinline__ u32 pack4_fp8(float a, float b, float c, float d) {
  u32 p = __builtin_amdgcn_cvt_pk_fp8_f32(a, b, 0, false);
  p = __builtin_amdgcn_cvt_pk_fp8_f32(c, d, p, true);
  return p;
}
__device__ __forceinline__ f32x2 unpk_lo(u32 v) {
  return __builtin_amdgcn_cvt_pk_f32_fp8(v, false);
}
__device__ __forceinline__ f32x2 unpk_hi(u32 v) {
  return __builtin_amdgcn_cvt_pk_f32_fp8(v, true);
}

#define GLD16(ldsptr, gptr)                                                     \
  __builtin_amdgcn_global_load_lds(                                             \
      (__attribute__((address_space(1))) void*)(gptr),                          \
      (__attribute__((address_space(3))) void*)(ldsptr), 16, 0, 0)

// ---------------------------------------------------------------------------
// reduce helpers
// ---------------------------------------------------------------------------
__device__ __forceinline__ float wave_red(float v) {
  for (int o = 32; o; o >>= 1) v += __shfl_down(v, o, 64);
  return v;
}

__device__ __forceinline__ float block_reduce1(float v) {
  __shared__ float buf[4];
  v = wave_red(v);
  int lane = threadIdx.x & 63, w = threadIdx.x >> 6;
  if (lane == 0) buf[w] = v;
  __syncthreads();
  float r = 0.f;
  if (threadIdx.x == 0) r = buf[0] + buf[1] + buf[2] + buf[3];
  return r;  // valid on thread 0
}

// ---------------------------------------------------------------------------
// node compaction: only nodes appearing in edges need H1/H2 rows (~86%).
// mark_nodes: mark[n]=1 for every edge endpoint.
// scan_nodes: single block, 256 thr x 32 entries; builds perm (compact->node),
//             slot (node->compact), countP[0] = count padded to 256.
// ---------------------------------------------------------------------------
__global__ void mark_nodes(const int* __restrict__ edges,
                           int* __restrict__ mark) {
  int t = blockIdx.x * blockDim.x + threadIdx.x;
  if (t < 2 * E_DIM) mark[edges[t]] = 1;
}

__global__ void scan_nodes(const int* __restrict__ mark, int* __restrict__ perm,
                           int* __restrict__ slot, int* __restrict__ countP) {
  const int t = threadIdx.x;
  const int base = t * 32;
  u32 bits = 0;
#pragma unroll
  for (int k = 0; k < 32; ++k) bits |= (mark[base + k] ? 1u : 0u) << k;
  int local = __popc(bits);
  // inclusive scan within wave
  const int lane = t & 63, w = t >> 6;
  int pre = local;
  for (int o = 1; o < 64; o <<= 1) {
    int g = __shfl_up(pre, o, 64);
    if (lane >= o) pre += g;
  }
  __shared__ int wsum[4];
  __shared__ int tot;
  if (lane == 63) wsum[w] = pre;
  __syncthreads();
  int wbase = 0;
  for (int i = 0; i < w; ++i) wbase += wsum[i];
  const int excl = wbase + pre - local;  // exclusive prefix for this thread
  int run = excl;
#pragma unroll
  for (int k = 0; k < 32; ++k)
    if (bits & (1u << k)) {
      slot[base + k] = run;
      perm[run] = base + k;
      run++;
    }
  if (t == 255) tot = excl + local;
  __syncthreads();
  const int count = tot;
  const int cpad = (count + 255) & ~255;
  for (int r = count + t; r < cpad; r += 256) perm[r] = 0;  // pad: dup node 0
  if (t == 0) countP[0] = cpad;
}

// ---------------------------------------------------------------------------
// gather-convert: A8c[r] = fp8(A[perm[r]]) for r < countP[0] (incl. padding)
// ---------------------------------------------------------------------------
__global__ void convert_gather(const float* __restrict__ A,
                               u8* __restrict__ A8c,
                               const int* __restrict__ perm,
                               const int* __restrict__ countP) {
  const int r = blockIdx.x;
  if (r >= countP[0]) return;
  const float4* row = (const float4*)(A + (size_t)perm[r] * N_DIM);
  u32* orow = (u32*)(A8c + (size_t)r * N_DIM);
#pragma unroll
  for (int t = 0; t < 8; ++t) {
    const int i = threadIdx.x + t * 256;
    float4 v = row[i];
    orow[i] = pack4_fp8(v.x, v.y, v.z, v.w);
  }
}

// ---------------------------------------------------------------------------
// fused: W1/W2 fp32->fp8 (*WSCALE) + row norms + b1/b2 norms, all * E.
// ---------------------------------------------------------------------------
__global__ void prep_w(const float* __restrict__ W1,
                       const float* __restrict__ W2,
                       const float* __restrict__ b1,
                       const float* __restrict__ b2, u8* __restrict__ W1_8,
                       u8* __restrict__ W2_8, float* __restrict__ out) {
  const int blk = blockIdx.x;
  if (blk < H_DIM) {  // W1 row: 8192 floats
    const float4* row = (const float4*)(W1 + (size_t)blk * N_DIM);
    u32* orow = (u32*)(W1_8 + (size_t)blk * N_DIM);
    float s = 0.f;
#pragma unroll
    for (int t = 0; t < 8; ++t) {
      int i = threadIdx.x + t * 256;
      float4 v = row[i];
      s += v.x * v.x + v.y * v.y + v.z * v.z + v.w * v.w;
      orow[i] = pack4_fp8(v.x * WSCALE, v.y * WSCALE, v.z * WSCALE,
                          v.w * WSCALE);
    }
    s = block_reduce1(s);
    if (threadIdx.x == 0) atomicAdd(out, sqrtf(s) * (float)E_DIM);
  } else if (blk < H_DIM + N_DIM / 4) {  // W2: 4 rows/block, 1024 floats each
    __shared__ float buf[4];
    const int wave = threadIdx.x >> 6, lane = threadIdx.x & 63;
    const int r = (blk - H_DIM) * 4 + wave;
    const float4* row = (const float4*)(W2 + (size_t)r * H_DIM);
    u32* orow = (u32*)(W2_8 + (size_t)r * H_DIM);
    float s = 0.f;
#pragma unroll
    for (int t = 0; t < 4; ++t) {
      int i = lane + t * 64;
      float4 v = row[i];
      s += v.x * v.x + v.y * v.y + v.z * v.z + v.w * v.w;
      orow[i] = pack4_fp8(v.x * WSCALE, v.y * WSCALE, v.z * WSCALE,
                          v.w * WSCALE);
    }
    s = wave_red(s);
    if (lane == 0) buf[wave] = sqrtf(s);
    __syncthreads();
    if (threadIdx.x == 0)
      atomicAdd(out, (buf[0] + buf[1] + buf[2] + buf[3]) * (float)E_DIM);
  } else if (blk == H_DIM + N_DIM / 4) {  // ||b1||
    const float4* row = (const float4*)b1;
    float4 v = row[threadIdx.x];
    float s = v.x * v.x + v.y * v.y + v.z * v.z + v.w * v.w;
    s = block_reduce1(s);
    if (threadIdx.x == 0) atomicAdd(out, sqrtf(s) * (float)E_DIM);
  } else {  // ||b2||
    const float4* row = (const float4*)b2;
    float s = 0.f;
#pragma unroll
    for (int t = 0; t < 8; ++t) {
      float4 v = row[threadIdx.x + t * 256];
      s += v.x * v.x + v.y * v.y + v.z * v.z + v.w * v.w;
    }
    s = block_reduce1(s);
    if (threadIdx.x == 0) atomicAdd(out, sqrtf(s) * (float)E_DIM);
  }
}

// ---------------------------------------------------------------------------
// GEMM1: 128x128 tile, verified 2-barrier structure, XCD-aware remap,
// early-exit for row-tiles beyond compact count. Rows of Ag are COMPACT.
// C = fp8( WSCALE * sigmoid( invScale*(A B^T) + bias ) ), swapped MFMA.
// ---------------------------------------------------------------------------
#define BM 128
#define BN 128
#define BKB 128

__global__ __launch_bounds__(256) void gemm_fp8_sigmoid(
    const u8* __restrict__ Ag,    // [Mp][K] compact
    const u8* __restrict__ Bg,    // [Nd][K]
    const float* __restrict__ bias,
    u8* __restrict__ Cg,          // [Mp][Nd] e4m3, value*WSCALE
    float invScale, int K, int Nd, const int* __restrict__ countP) {
  __shared__ __align__(16) u8 Xs[BM * BKB];
  __shared__ __align__(16) u8 Ws[BN * BKB];

  // bijective XCD remap: XCD k gets contiguous chunk of flat ids (nwg%8==0)
  const int nwg = gridDim.x * gridDim.y;
  const int id = blockIdx.y * gridDim.x + blockIdx.x;
  const int wg = (id & 7) * (nwg >> 3) + (id >> 3);
  const int bx = wg % gridDim.x;
  const int by = wg / gridDim.x;

  const int Mp = countP[0];
  if (by * BM >= Mp) return;  // dead row-tile (beyond compact node count)

  const int tid = threadIdx.x;
  const int wave = tid >> 6, lane = tid & 63;
  const int wr = wave >> 1, wc = wave & 1;
  const size_t rowBase = (size_t)by * BM;
  const size_t colBase = (size_t)bx * BN;

  f32x4 acc[4][4] = {};

  const int i8 = lane >> 3;  // row within 8-row staging group
  const int c8 = lane & 7;   // LDS 16-B slot
  const int sw = c8 ^ i8;    // swizzled global 16-B unit

  const int quad = lane >> 4;
  const int m15 = lane & 15;

  for (int k0 = 0; k0 < K; k0 += BKB) {
#pragma unroll
    for (int j = 0; j < 4; ++j) {
      const int r0 = (wave * 4 + j) * 8;
      const u8* gx = Ag + (rowBase + r0 + i8) * (size_t)K + (k0 + sw * 16);
      GLD16(&Xs[r0 * BKB], gx);
      const u8* gw = Bg + (colBase + r0 + i8) * (size_t)K + (k0 + sw * 16);
      GLD16(&Ws[r0 * BKB], gw);
    }
    __syncthreads();

    i32x8 af[4], bfr[4];
#pragma unroll
    for (int t = 0; t < 4; ++t) {
      const int m = wr * 64 + t * 16 + m15;
      i32x4 alo = *(const i32x4*)&Xs[m * BKB + ((2 * quad) ^ (m & 7)) * 16];
      i32x4 ahi = *(const i32x4*)&Xs[m * BKB + ((2 * quad + 1) ^ (m & 7)) * 16];
      af[t] = __builtin_shufflevector(alo, ahi, 0, 1, 2, 3, 4, 5, 6, 7);
      const int n = wc * 64 + t * 16 + m15;
      i32x4 blo = *(const i32x4*)&Ws[n * BKB + ((2 * quad) ^ (n & 7)) * 16];
      i32x4 bhi = *(const i32x4*)&Ws[n * BKB + ((2 * quad + 1) ^ (n & 7)) * 16];
      bfr[t] = __builtin_shufflevector(blo, bhi, 0, 1, 2, 3, 4, 5, 6, 7);
    }
#pragma unroll
    for (int mt = 0; mt < 4; ++mt)
#pragma unroll
      for (int nt = 0; nt < 4; ++nt)
        acc[mt][nt] = __builtin_amdgcn_mfma_scale_f32_16x16x128_f8f6f4(
            bfr[nt], af[mt], acc[mt][nt], 0, 0,
            0, 0x7F7F7F7F, 0, 0x7F7F7F7F);  // SWAPPED: D[n][m] layout
    __syncthreads();
  }

  // epilogue: lane owns C row (mt*16+m15), cols nt*16+quad*4+{0..3}
  f32x4 bv4[4];
#pragma unroll
  for (int nt = 0; nt < 4; ++nt)
    bv4[nt] = *(const f32x4*)&bias[colBase + wc * 64 + nt * 16 + quad * 4];
#pragma unroll
  for (int mt = 0; mt < 4; ++mt) {
    const size_t grow = rowBase + wr * 64 + mt * 16 + m15;
    u32* crow = (u32*)(Cg + grow * (size_t)Nd + colBase + wc * 64);
#pragma unroll
    for (int nt = 0; nt < 4; ++nt) {
      float v[4];
#pragma unroll
      for (int i = 0; i < 4; ++i) {
        float x = acc[mt][nt][i] * invScale + bv4[nt][i];
        v[i] = WSCALE / (1.0f + __expf(-x));
      }
      crow[nt * 4 + quad] = pack4_fp8(v[0], v[1], v[2], v[3]);
    }
  }
}

// ---------------------------------------------------------------------------
// GEMM2: 256x256 tile, 8 waves (2x4), double-buffered LDS (128 KB), 1 blk/CU.
// 2-phase: next K-tile's global_load_lds issued BEFORE current tile compute.
// T5 setprio around the MFMA cluster (stage-vs-compute wave role diversity).
// Rows of Ag (H1) and Cg (H2) are COMPACT; early-exit beyond compact count.
// ---------------------------------------------------------------------------
#define BM2 256
#define BN2 256

__global__ __launch_bounds__(512, 2) void gemm2_fp8_sigmoid(
    const u8* __restrict__ Ag,    // [Mp][K]  (H1 compact)
    const u8* __restrict__ Bg,    // [Nd][K]  (W2)
    const float* __restrict__ bias,
    u8* __restrict__ Cg,          // [Mp][Nd] e4m3, value*WSCALE
    float invScale, int K, int Nd, const int* __restrict__ countP) {
  __shared__ __align__(16) u8 Xs[2][BM2 * BKB];   // 2 x 32 KB
  __shared__ __align__(16) u8 Ws[2][BN2 * BKB];   // 2 x 32 KB

  const int Mp = countP[0];
  if ((int)blockIdx.y * BM2 >= Mp) return;  // dead row-tile

  const int tid = threadIdx.x;
  const int wave = tid >> 6, lane = tid & 63;
  const int wr = wave >> 2;          // 0..1 -> 128-row half
  const int wc = wave & 3;           // 0..3 -> 64-col quarter
  const size_t rowBase = (size_t)blockIdx.y * BM2;
  const size_t colBase = (size_t)blockIdx.x * BN2;

  f32x4 acc[8][4] = {};

  const int i8 = lane >> 3;
  const int c8 = lane & 7;
  const int sw = c8 ^ i8;            // swizzled global 16-B unit (key: row&7)
  const int quad = lane >> 4;
  const int m15 = lane & 15;

  const int T = K / BKB;

  auto STAGE = [&](int kt, int b) {
    const size_t kOff = (size_t)kt * BKB + sw * 16;
#pragma unroll
    for (int j = 0; j < 4; ++j) {
      const int r0 = (wave * 4 + j) * 8;  // 8 waves * 4 * 8 = 256 rows
      GLD16(&Xs[b][r0 * BKB], Ag + (rowBase + r0 + i8) * (size_t)K + kOff);
      GLD16(&Ws[b][r0 * BKB], Bg + (colBase + r0 + i8) * (size_t)K + kOff);
    }
  };

  STAGE(0, 0);
  __syncthreads();

  for (int t = 0; t < T; ++t) {
    const int cur = t & 1;
    if (t + 1 < T) STAGE(t + 1, cur ^ 1);  // in flight across this tile's MFMA

    const u8* Xb = Xs[cur];
    const u8* Wb = Ws[cur];

    i32x8 bfr[4];
#pragma unroll
    for (int nt = 0; nt < 4; ++nt) {
      const int n = wc * 64 + nt * 16 + m15;
      i32x4 blo = *(const i32x4*)&Wb[n * BKB + ((2 * quad) ^ (n & 7)) * 16];
      i32x4 bhi = *(const i32x4*)&Wb[n * BKB + ((2 * quad + 1) ^ (n & 7)) * 16];
      bfr[nt] = __builtin_shufflevector(blo, bhi, 0, 1, 2, 3, 4, 5, 6, 7);
    }
    __builtin_amdgcn_s_setprio(1);
#pragma unroll
    for (int mt = 0; mt < 8; ++mt) {
      const int m = wr * 128 + mt * 16 + m15;
      i32x4 alo = *(const i32x4*)&Xb[m * BKB + ((2 * quad) ^ (m & 7)) * 16];
      i32x4 ahi = *(const i32x4*)&Xb[m * BKB + ((2 * quad + 1) ^ (m & 7)) * 16];
      i32x8 af = __builtin_shufflevector(alo, ahi, 0, 1, 2, 3, 4, 5, 6, 7);
#pragma unroll
      for (int nt = 0; nt < 4; ++nt)
        acc[mt][nt] = __builtin_amdgcn_mfma_scale_f32_16x16x128_f8f6f4(
            bfr[nt], af, acc[mt][nt], 0, 0,
            0, 0x7F7F7F7F, 0, 0x7F7F7F7F);  // SWAPPED: lane owns C-row m
    }
    __builtin_amdgcn_s_setprio(0);
    __syncthreads();  // drains this wave's t+1 loads + fences buf reuse
  }

  // epilogue: lane owns C row (wr*128+mt*16+m15), cols wc*64+nt*16+quad*4+i
  f32x4 bv4[4];
#pragma unroll
  for (int nt = 0; nt < 4; ++nt)
    bv4[nt] = *(const f32x4*)&bias[colBase + wc * 64 + nt * 16 + quad * 4];
#pragma unroll
  for (int mt = 0; mt < 8; ++mt) {
    const size_t grow = rowBase + wr * 128 + mt * 16 + m15;
    u32* crow = (u32*)(Cg + grow * (size_t)Nd + colBase + wc * 64);
#pragma unroll
    for (int nt = 0; nt < 4; ++nt) {
      float v[4];
#pragma unroll
      for (int i = 0; i < 4; ++i) {
        float x = acc[mt][nt][i] * invScale + bv4[nt][i];
        v[i] = WSCALE / (1.0f + __expf(-x));
      }
      crow[nt * 4 + quad] = pack4_fp8(v[0], v[1], v[2], v[3]);
    }
  }
}

// ---------------------------------------------------------------------------
// loss_1 layer-1: one WAVE per edge (4 edges/block); early-exit label==0.
// H1 rows are compact -> index via slot[].
// ---------------------------------------------------------------------------
__global__ void edge_loss_h(const u8* __restrict__ H1,
                            const int* __restrict__ edges,
                            const int* __restrict__ labels,
                            const int* __restrict__ slot,
                            float* __restrict__ out) {
  __shared__ float buf[4];
  const int wave = threadIdx.x >> 6, lane = threadIdx.x & 63;
  const int e = blockIdx.x * 4 + wave;
  float r = 0.f;
  if (labels[e] != 0) {
    const int ni = slot[edges[e * 2]], nj = slot[edges[e * 2 + 1]];
    const i32x4 a = ((const i32x4*)(H1 + (size_t)ni * H_DIM))[lane];
    const i32x4 b = ((const i32x4*)(H1 + (size_t)nj * H_DIM))[lane];
    float s = 0.f;
#pragma unroll
    for (int j = 0; j < 4; ++j) {
      f32x2 al = unpk_lo((u32)a[j]), ah = unpk_hi((u32)a[j]);
      f32x2 bl = unpk_lo((u32)b[j]), bh = unpk_hi((u32)b[j]);
      float d0 = al.x - bl.x, d1 = al.y - bl.y;
      float d2 = ah.x - bh.x, d3 = ah.y - bh.y;
      s += d0 * d0 + d1 * d1 + d2 * d2 + d3 * d3;
    }
    s = wave_red(s);
    r = sqrtf(s) * INV_WSCALE;
  }
  if (lane == 0) buf[wave] = r;
  __syncthreads();
  if (threadIdx.x == 0) atomicAdd(out, buf[0] + buf[1] + buf[2] + buf[3]);
}

// ---------------------------------------------------------------------------
// loss_1 layer-2 + loss_2: one WAVE per edge. H2/A8 rows compact via slot[].
// ---------------------------------------------------------------------------
__global__ void edge_loss_final(const u8* __restrict__ H2,
                                const u8* __restrict__ A8,
                                const int* __restrict__ edges,
                                const int* __restrict__ labels,
                                const int* __restrict__ slot,
                                float* __restrict__ out) {
  __shared__ float buf[4];
  const int wave = threadIdx.x >> 6, lane = threadIdx.x & 63;
  const int e = blockIdx.x * 4 + wave;
  const int ni = slot[edges[e * 2]], nj = slot[edges[e * 2 + 1]];
  const i32x4* hi = (const i32x4*)(H2 + (size_t)ni * N_DIM);
  const i32x4* hj = (const i32x4*)(H2 + (size_t)nj * N_DIM);
  const i32x4* xi = (const i32x4*)(A8 + (size_t)ni * N_DIM);
  const i32x4* xj = (const i32x4*)(A8 + (size_t)nj * N_DIM);
  float s12 = 0.f, si = 0.f, sj = 0.f;
#pragma unroll 2
  for (int t = 0; t < 8; ++t) {
    const int idx = lane + t * 64;
    i32x4 a = hi[idx], b = hj[idx], x = xi[idx], y = xj[idx];
#pragma unroll
    for (int j = 0; j < 4; ++j) {
      f32x2 al = unpk_lo((u32)a[j]), ah = unpk_hi((u32)a[j]);
      f32x2 bl = unpk_lo((u32)b[j]), bh = unpk_hi((u32)b[j]);
      f32x2 xl = unpk_lo((u32)x[j]), xh = unpk_hi((u32)x[j]);
      f32x2 yl = unpk_lo((u32)y[j]), yh = unpk_hi((u32)y[j]);
      float d;
      d = al.x - bl.x; s12 += d * d;
      d = al.y - bl.y; s12 += d * d;
      d = ah.x - bh.x; s12 += d * d;
      d = ah.y - bh.y; s12 += d * d;
      d = WSCALE * xl.x - al.x; si += d * d;
      d = WSCALE * xl.y - al.y; si += d * d;
      d = WSCALE * xh.x - ah.x; si += d * d;
      d = WSCALE * xh.y - ah.y; si += d * d;
      d = WSCALE * yl.x - bl.x; sj += d * d;
      d = WSCALE * yl.y - bl.y; sj += d * d;
      d = WSCALE * yh.x - bh.x; sj += d * d;
      d = WSCALE * yh.y - bh.y; sj += d * d;
    }
  }
  for (int o = 32; o; o >>= 1) {
    s12 += __shfl_down(s12, o, 64);
    si += __shfl_down(si, o, 64);
    sj += __shfl_down(sj, o, 64);
  }
  if (lane == 0) {
    float lab = (labels[e] != 0) ? 1.f : 0.f;
    float fac = (labels[e] != 0) ? PENALTY_F : 1.f;
    buf[wave] = (lab * sqrtf(s12) + fac * (sqrtf(si) + sqrtf(sj))) * INV_WSCALE;
  }
  __syncthreads();
  if (threadIdx.x == 0) atomicAdd(out, buf[0] + buf[1] + buf[2] + buf[3]);
}

// ---------------------------------------------------------------------------
extern "C" void kernel_launch(void* const* d_in, const int* in_sizes, int n_in,
                              void* d_out, int out_size, void* d_ws,
                              size_t ws_size, hipStream_t stream) {
  const float* A = (const float*)d_in[0];
  const float* W1 = (const float*)d_in[1];
  const float* b1 = (const float*)d_in[2];
  const float* W2 = (const float*)d_in[3];
  const float* b2 = (const float*)d_in[4];
  const int* edges = (const int*)d_in[5];
  const int* labels = (const int*)d_in[6];
  float* out = (float*)d_out;

  // workspace layout (bytes), ~160 MB
  char* ws = (char*)d_ws;
  u8* A8c  = (u8*)(ws);                       // Mp x N fp8    64 MB (compact)
  u8* H1c  = (u8*)(ws + 67108864ull);         // Mp x H fp8     8 MB (compact)
  u8* H2c  = (u8*)(ws + 75497472ull);         // Mp x N fp8    64 MB (compact)
  u8* W1_8 = (u8*)(ws + 142606336ull);        // H x N fp8      8 MB
  u8* W2_8 = (u8*)(ws + 150994944ull);        // N x H fp8      8 MB
  int* mark   = (int*)(ws + 159383552ull);    // 32 KB
  int* perm   = (int*)(ws + 159416320ull);    // 32 KB
  int* slot   = (int*)(ws + 159449088ull);    // 32 KB
  int* countP = (int*)(ws + 159481856ull);    // 4 B

  hipMemsetAsync(out, 0, sizeof(float), stream);
  hipMemsetAsync(mark, 0, N_DIM * sizeof(int), stream);

  // node compaction
  mark_nodes<<<(2 * E_DIM) / 256, 256, 0, stream>>>(edges, mark);
  scan_nodes<<<1, 256, 0, stream>>>(mark, perm, slot, countP);

  // A rows (compact, gathered) -> fp8
  convert_gather<<<N_DIM, 256, 0, stream>>>(A, A8c, perm, countP);

  // W1/W2 convert (*16) fused with row norms; b1/b2 norms; all *E, exact fp32
  prep_w<<<H_DIM + N_DIM / 4 + 2, 256, 0, stream>>>(W1, W2, b1, b2, W1_8,
                                                    W2_8, out);

  // layer 1: H1c = sigmoid(A8c @ W1^T + b1)   [Mp x H]  128^2 tiles
  gemm_fp8_sigmoid<<<dim3(H_DIM / BN, N_DIM / BM), 256, 0, stream>>>(
      A8c, W1_8, b1, H1c, INV_WSCALE, N_DIM, H_DIM, countP);
  edge_loss_h<<<E_DIM / 4, 256, 0, stream>>>(H1c, edges, labels, slot, out);

  // layer 2: H2c = sigmoid(H1c @ W2^T + b2)  [Mp x N]  256^2 2-phase
  gemm2_fp8_sigmoid<<<dim3(N_DIM / BN2, N_DIM / BM2), 512, 0, stream>>>(
      H1c, W2_8, b2, H2c, INV_WSCALE * INV_WSCALE, H_DIM, N_DIM, countP);
  edge_loss_final<<<E_DIM / 4, 256, 0, stream>>>(H2c, A8c, edges, labels, slot,
                                                 out);
}

// Round 6
// 653.752 us; speedup vs baseline: 1.1137x; 1.1137x over previous
//
#include <hip/hip_runtime.h>
#include <hip/hip_bf16.h>
#include <stdint.h>

#define N_DIM 8192
#define H_DIM 1024
#define E_DIM 8192
#define PENALTY_F 10.0f
#define WSCALE 16.0f      // weights and H outputs stored *16 in e4m3
#define INV_WSCALE 0.0625f

typedef unsigned short u16;
typedef unsigned char u8;
typedef unsigned int u32;
typedef __attribute__((ext_vector_type(4))) float f32x4;
typedef __attribute__((ext_vector_type(2))) float f32x2;
typedef __attribute__((ext_vector_type(4))) int i32x4;
typedef __attribute__((ext_vector_type(8))) int i32x8;

// pack 4 floats -> 4 e4m3 bytes (OCP on gfx950)
__device__ __forceinline__ u32 pack4_fp8(float a, float b, float c, float d) {
  u32 p = __builtin_amdgcn_cvt_pk_fp8_f32(a, b, 0, false);
  p = __builtin_amdgcn_cvt_pk_fp8_f32(c, d, p, true);
  return p;
}
__device__ __forceinline__ f32x2 unpk_lo(u32 v) {
  return __builtin_amdgcn_cvt_pk_f32_fp8(v, false);
}
__device__ __forceinline__ f32x2 unpk_hi(u32 v) {
  return __builtin_amdgcn_cvt_pk_f32_fp8(v, true);
}

#define GLD16(ldsptr, gptr)                                                     \
  __builtin_amdgcn_global_load_lds(                                             \
      (__attribute__((address_space(1))) void*)(gptr),                          \
      (__attribute__((address_space(3))) void*)(ldsptr), 16, 0, 0)

// partial-slot accumulator: 64 slots, 64-B stride, summed by finalize_sum.
#define PSLOT(part) (&(part)[(blockIdx.x & 63) * 16])

// ---------------------------------------------------------------------------
// reduce helpers
// ---------------------------------------------------------------------------
__device__ __forceinline__ float wave_red(float v) {
  for (int o = 32; o; o >>= 1) v += __shfl_down(v, o, 64);
  return v;
}

__device__ __forceinline__ float block_reduce1(float v) {
  __shared__ float buf[4];
  v = wave_red(v);
  int lane = threadIdx.x & 63, w = threadIdx.x >> 6;
  if (lane == 0) buf[w] = v;
  __syncthreads();
  float r = 0.f;
  if (threadIdx.x == 0) r = buf[0] + buf[1] + buf[2] + buf[3];
  return r;  // valid on thread 0
}

// ---------------------------------------------------------------------------
// fp32 -> fp8 (A; scale 1), grid-stride (2048 blocks)
// ---------------------------------------------------------------------------
__global__ void convert_f32_fp8(const float* __restrict__ in,
                                u8* __restrict__ out, int n4, float scale) {
  const int stride = gridDim.x * blockDim.x;
  for (int i = blockIdx.x * blockDim.x + threadIdx.x; i < n4; i += stride) {
    float4 v = ((const float4*)in)[i];
    ((u32*)out)[i] =
        pack4_fp8(v.x * scale, v.y * scale, v.z * scale, v.w * scale);
  }
}

// ---------------------------------------------------------------------------
// fused: W1/W2 fp32->fp8 (*WSCALE) + row norms + b1/b2 norms, all * E.
// Atomic adds go to the 64-slot partial buffer (single-address congestion fix).
// ---------------------------------------------------------------------------
__global__ void prep_w(const float* __restrict__ W1,
                       const float* __restrict__ W2,
                       const float* __restrict__ b1,
                       const float* __restrict__ b2, u8* __restrict__ W1_8,
                       u8* __restrict__ W2_8, float* __restrict__ part) {
  const int blk = blockIdx.x;
  float* slotp = PSLOT(part);
  if (blk < H_DIM) {  // W1 row: 8192 floats
    const float4* row = (const float4*)(W1 + (size_t)blk * N_DIM);
    u32* orow = (u32*)(W1_8 + (size_t)blk * N_DIM);
    float s = 0.f;
#pragma unroll
    for (int t = 0; t < 8; ++t) {
      int i = threadIdx.x + t * 256;
      float4 v = row[i];
      s += v.x * v.x + v.y * v.y + v.z * v.z + v.w * v.w;
      orow[i] = pack4_fp8(v.x * WSCALE, v.y * WSCALE, v.z * WSCALE,
                          v.w * WSCALE);
    }
    s = block_reduce1(s);
    if (threadIdx.x == 0) atomicAdd(slotp, sqrtf(s) * (float)E_DIM);
  } else if (blk < H_DIM + N_DIM / 4) {  // W2: 4 rows/block, 1024 floats each
    __shared__ float buf[4];
    const int wave = threadIdx.x >> 6, lane = threadIdx.x & 63;
    const int r = (blk - H_DIM) * 4 + wave;
    const float4* row = (const float4*)(W2 + (size_t)r * H_DIM);
    u32* orow = (u32*)(W2_8 + (size_t)r * H_DIM);
    float s = 0.f;
#pragma unroll
    for (int t = 0; t < 4; ++t) {
      int i = lane + t * 64;
      float4 v = row[i];
      s += v.x * v.x + v.y * v.y + v.z * v.z + v.w * v.w;
      orow[i] = pack4_fp8(v.x * WSCALE, v.y * WSCALE, v.z * WSCALE,
                          v.w * WSCALE);
    }
    s = wave_red(s);
    if (lane == 0) buf[wave] = sqrtf(s);
    __syncthreads();
    if (threadIdx.x == 0)
      atomicAdd(slotp, (buf[0] + buf[1] + buf[2] + buf[3]) * (float)E_DIM);
  } else if (blk == H_DIM + N_DIM / 4) {  // ||b1||
    const float4* row = (const float4*)b1;
    float4 v = row[threadIdx.x];
    float s = v.x * v.x + v.y * v.y + v.z * v.z + v.w * v.w;
    s = block_reduce1(s);
    if (threadIdx.x == 0) atomicAdd(slotp, sqrtf(s) * (float)E_DIM);
  } else {  // ||b2||
    const float4* row = (const float4*)b2;
    float s = 0.f;
#pragma unroll
    for (int t = 0; t < 8; ++t) {
      float4 v = row[threadIdx.x + t * 256];
      s += v.x * v.x + v.y * v.y + v.z * v.z + v.w * v.w;
    }
    s = block_reduce1(s);
    if (threadIdx.x == 0) atomicAdd(slotp, sqrtf(s) * (float)E_DIM);
  }
}

// ---------------------------------------------------------------------------
// GEMM1: 128x128 tile, verified 2-barrier structure, XCD-aware remap.
// C = fp8( WSCALE * sigmoid( invScale*(A B^T) + bias ) ), swapped MFMA.
// ---------------------------------------------------------------------------
#define BM 128
#define BN 128
#define BKB 128

__global__ __launch_bounds__(256) void gemm_fp8_sigmoid(
    const u8* __restrict__ Ag,    // [M][K]
    const u8* __restrict__ Bg,    // [Nd][K]
    const float* __restrict__ bias,
    u8* __restrict__ Cg,          // [M][Nd] e4m3, value*WSCALE
    float invScale, int K, int Nd) {
  __shared__ __align__(16) u8 Xs[BM * BKB];
  __shared__ __align__(16) u8 Ws[BN * BKB];

  // bijective XCD remap: XCD k gets contiguous chunk of flat ids (nwg%8==0)
  const int nwg = gridDim.x * gridDim.y;
  const int id = blockIdx.y * gridDim.x + blockIdx.x;
  const int wg = (id & 7) * (nwg >> 3) + (id >> 3);
  const int bx = wg % gridDim.x;
  const int by = wg / gridDim.x;

  const int tid = threadIdx.x;
  const int wave = tid >> 6, lane = tid & 63;
  const int wr = wave >> 1, wc = wave & 1;
  const size_t rowBase = (size_t)by * BM;
  const size_t colBase = (size_t)bx * BN;

  f32x4 acc[4][4] = {};

  const int i8 = lane >> 3;  // row within 8-row staging group
  const int c8 = lane & 7;   // LDS 16-B slot
  const int sw = c8 ^ i8;    // swizzled global 16-B unit

  const int quad = lane >> 4;
  const int m15 = lane & 15;

  for (int k0 = 0; k0 < K; k0 += BKB) {
#pragma unroll
    for (int j = 0; j < 4; ++j) {
      const int r0 = (wave * 4 + j) * 8;
      const u8* gx = Ag + (rowBase + r0 + i8) * (size_t)K + (k0 + sw * 16);
      GLD16(&Xs[r0 * BKB], gx);
      const u8* gw = Bg + (colBase + r0 + i8) * (size_t)K + (k0 + sw * 16);
      GLD16(&Ws[r0 * BKB], gw);
    }
    __syncthreads();

    i32x8 af[4], bfr[4];
#pragma unroll
    for (int t = 0; t < 4; ++t) {
      const int m = wr * 64 + t * 16 + m15;
      i32x4 alo = *(const i32x4*)&Xs[m * BKB + ((2 * quad) ^ (m & 7)) * 16];
      i32x4 ahi = *(const i32x4*)&Xs[m * BKB + ((2 * quad + 1) ^ (m & 7)) * 16];
      af[t] = __builtin_shufflevector(alo, ahi, 0, 1, 2, 3, 4, 5, 6, 7);
      const int n = wc * 64 + t * 16 + m15;
      i32x4 blo = *(const i32x4*)&Ws[n * BKB + ((2 * quad) ^ (n & 7)) * 16];
      i32x4 bhi = *(const i32x4*)&Ws[n * BKB + ((2 * quad + 1) ^ (n & 7)) * 16];
      bfr[t] = __builtin_shufflevector(blo, bhi, 0, 1, 2, 3, 4, 5, 6, 7);
    }
#pragma unroll
    for (int mt = 0; mt < 4; ++mt)
#pragma unroll
      for (int nt = 0; nt < 4; ++nt)
        acc[mt][nt] = __builtin_amdgcn_mfma_scale_f32_16x16x128_f8f6f4(
            bfr[nt], af[mt], acc[mt][nt], 0, 0,
            0, 0x7F7F7F7F, 0, 0x7F7F7F7F);  // SWAPPED: D[n][m] layout
    __syncthreads();
  }

  // epilogue: lane owns C row (mt*16+m15), cols nt*16+quad*4+{0..3}
  f32x4 bv4[4];
#pragma unroll
  for (int nt = 0; nt < 4; ++nt)
    bv4[nt] = *(const f32x4*)&bias[colBase + wc * 64 + nt * 16 + quad * 4];
#pragma unroll
  for (int mt = 0; mt < 4; ++mt) {
    const size_t grow = rowBase + wr * 64 + mt * 16 + m15;
    u32* crow = (u32*)(Cg + grow * (size_t)Nd + colBase + wc * 64);
#pragma unroll
    for (int nt = 0; nt < 4; ++nt) {
      float v[4];
#pragma unroll
      for (int i = 0; i < 4; ++i) {
        float x = acc[mt][nt][i] * invScale + bv4[nt][i];
        v[i] = WSCALE / (1.0f + __expf(-x));
      }
      crow[nt * 4 + quad] = pack4_fp8(v[0], v[1], v[2], v[3]);
    }
  }
}

// ---------------------------------------------------------------------------
// GEMM2: 256x256 tile, 8 waves (2x4), double-buffered LDS (128 KB), 1 blk/CU.
// 2-phase pipeline + T5 setprio. Epilogue also accumulates
// nd2[row] = sum_cols (WSCALE*A8[row][c] - H2q[row][c])^2 using the QUANTIZED
// H2 values (unpack of the just-packed fp8 -> bit-identical to what
// edge_loss_final previously re-read), reduced via LDS overlay of Xs.
// ---------------------------------------------------------------------------
#define BM2 256
#define BN2 256

__global__ __launch_bounds__(512, 2) void gemm2_fp8_sigmoid(
    const u8* __restrict__ Ag,    // [M][K]  (H1)
    const u8* __restrict__ Bg,    // [Nd][K] (W2)
    const float* __restrict__ bias,
    u8* __restrict__ Cg,          // [M][Nd] e4m3, value*WSCALE
    const u8* __restrict__ A8,    // [M][Nd] e4m3 (X, scale 1)
    float* __restrict__ nd2,      // [M] per-node sum of squares (pre-zeroed)
    float invScale, int K, int Nd) {
  __shared__ __align__(16) u8 Xs[2][BM2 * BKB];   // 2 x 32 KB
  __shared__ __align__(16) u8 Ws[2][BN2 * BKB];   // 2 x 32 KB

  const int tid = threadIdx.x;
  const int wave = tid >> 6, lane = tid & 63;
  const int wr = wave >> 2;          // 0..1 -> 128-row half
  const int wc = wave & 3;           // 0..3 -> 64-col quarter
  const size_t rowBase = (size_t)blockIdx.y * BM2;
  const size_t colBase = (size_t)blockIdx.x * BN2;

  f32x4 acc[8][4] = {};

  const int i8 = lane >> 3;
  const int c8 = lane & 7;
  const int sw = c8 ^ i8;            // swizzled global 16-B unit (key: row&7)
  const int quad = lane >> 4;
  const int m15 = lane & 15;

  const int T = K / BKB;

  auto STAGE = [&](int kt, int b) {
    const size_t kOff = (size_t)kt * BKB + sw * 16;
#pragma unroll
    for (int j = 0; j < 4; ++j) {
      const int r0 = (wave * 4 + j) * 8;  // 8 waves * 4 * 8 = 256 rows
      GLD16(&Xs[b][r0 * BKB], Ag + (rowBase + r0 + i8) * (size_t)K + kOff);
      GLD16(&Ws[b][r0 * BKB], Bg + (colBase + r0 + i8) * (size_t)K + kOff);
    }
  };

  STAGE(0, 0);
  __syncthreads();

  for (int t = 0; t < T; ++t) {
    const int cur = t & 1;
    if (t + 1 < T) STAGE(t + 1, cur ^ 1);  // in flight across this tile's MFMA

    const u8* Xb = Xs[cur];
    const u8* Wb = Ws[cur];

    i32x8 bfr[4];
#pragma unroll
    for (int nt = 0; nt < 4; ++nt) {
      const int n = wc * 64 + nt * 16 + m15;
      i32x4 blo = *(const i32x4*)&Wb[n * BKB + ((2 * quad) ^ (n & 7)) * 16];
      i32x4 bhi = *(const i32x4*)&Wb[n * BKB + ((2 * quad + 1) ^ (n & 7)) * 16];
      bfr[nt] = __builtin_shufflevector(blo, bhi, 0, 1, 2, 3, 4, 5, 6, 7);
    }
    __builtin_amdgcn_s_setprio(1);
#pragma unroll
    for (int mt = 0; mt < 8; ++mt) {
      const int m = wr * 128 + mt * 16 + m15;
      i32x4 alo = *(const i32x4*)&Xb[m * BKB + ((2 * quad) ^ (m & 7)) * 16];
      i32x4 ahi = *(const i32x4*)&Xb[m * BKB + ((2 * quad + 1) ^ (m & 7)) * 16];
      i32x8 af = __builtin_shufflevector(alo, ahi, 0, 1, 2, 3, 4, 5, 6, 7);
#pragma unroll
      for (int nt = 0; nt < 4; ++nt)
        acc[mt][nt] = __builtin_amdgcn_mfma_scale_f32_16x16x128_f8f6f4(
            bfr[nt], af, acc[mt][nt], 0, 0,
            0, 0x7F7F7F7F, 0, 0x7F7F7F7F);  // SWAPPED: lane owns C-row m
    }
    __builtin_amdgcn_s_setprio(0);
    __syncthreads();  // drains this wave's t+1 loads + fences buf reuse
  }

  // ---- epilogue: store H2 fp8 + accumulate nd2 per row ----
  // K-loop's trailing __syncthreads => LDS free; overlay Xs with ndbuf[256].
  float* ndbuf = (float*)&Xs[0][0];
  if (tid < 256) ndbuf[tid] = 0.f;
  __syncthreads();

  f32x4 bv4[4];
#pragma unroll
  for (int nt = 0; nt < 4; ++nt)
    bv4[nt] = *(const f32x4*)&bias[colBase + wc * 64 + nt * 16 + quad * 4];
#pragma unroll
  for (int mt = 0; mt < 8; ++mt) {
    const int rowLocal = wr * 128 + mt * 16 + m15;  // 0..255
    const size_t grow = rowBase + rowLocal;
    u32* crow = (u32*)(Cg + grow * (size_t)Nd + colBase + wc * 64);
    const u32* arow = (const u32*)(A8 + grow * (size_t)Nd + colBase + wc * 64);
    float nds = 0.f;
#pragma unroll
    for (int nt = 0; nt < 4; ++nt) {
      float v[4];
#pragma unroll
      for (int i = 0; i < 4; ++i) {
        float x = acc[mt][nt][i] * invScale + bv4[nt][i];
        v[i] = WSCALE / (1.0f + __expf(-x));
      }
      const u32 packed = pack4_fp8(v[0], v[1], v[2], v[3]);
      crow[nt * 4 + quad] = packed;
      // quantized H2 values (exactly what edge_loss_final would re-read)
      f32x2 hlo = unpk_lo(packed), hhi = unpk_hi(packed);
      const u32 xa = arow[nt * 4 + quad];
      f32x2 xlo = unpk_lo(xa), xhi = unpk_hi(xa);
      float d;
      d = WSCALE * xlo.x - hlo.x; nds += d * d;
      d = WSCALE * xlo.y - hlo.y; nds += d * d;
      d = WSCALE * xhi.x - hhi.x; nds += d * d;
      d = WSCALE * xhi.y - hhi.y; nds += d * d;
    }
    atomicAdd(&ndbuf[rowLocal], nds);  // LDS atomic, 4 waves/row collide
  }
  __syncthreads();
  if (tid < 256) atomicAdd(&nd2[rowBase + tid], ndbuf[tid]);
}

// ---------------------------------------------------------------------------
// loss_1 layer-1: one WAVE per edge (4 edges/block); early-exit label==0.
// ---------------------------------------------------------------------------
__global__ void edge_loss_h(const u8* __restrict__ H1,
                            const int* __restrict__ edges,
                            const int* __restrict__ labels,
                            float* __restrict__ part) {
  __shared__ float buf[4];
  const int wave = threadIdx.x >> 6, lane = threadIdx.x & 63;
  const int e = blockIdx.x * 4 + wave;
  float r = 0.f;
  if (labels[e] != 0) {
    const int ni = edges[e * 2], nj = edges[e * 2 + 1];
    const i32x4 a = ((const i32x4*)(H1 + (size_t)ni * H_DIM))[lane];
    const i32x4 b = ((const i32x4*)(H1 + (size_t)nj * H_DIM))[lane];
    float s = 0.f;
#pragma unroll
    for (int j = 0; j < 4; ++j) {
      f32x2 al = unpk_lo((u32)a[j]), ah = unpk_hi((u32)a[j]);
      f32x2 bl = unpk_lo((u32)b[j]), bh = unpk_hi((u32)b[j]);
      float d0 = al.x - bl.x, d1 = al.y - bl.y;
      float d2 = ah.x - bh.x, d3 = ah.y - bh.y;
      s += d0 * d0 + d1 * d1 + d2 * d2 + d3 * d3;
    }
    s = wave_red(s);
    r = sqrtf(s) * INV_WSCALE;
  }
  if (lane == 0) buf[wave] = r;
  __syncthreads();
  if (threadIdx.x == 0)
    atomicAdd(PSLOT(part), buf[0] + buf[1] + buf[2] + buf[3]);
}

// ---------------------------------------------------------------------------
// loss_1 layer-2 + loss_2: one WAVE per edge. Reads 2 H2 rows (pairwise s12)
// + precomputed nd2 scalars (the ||X-H2|| per-node term from GEMM2 epilogue).
// ---------------------------------------------------------------------------
__global__ void edge_loss_final(const u8* __restrict__ H2,
                                const float* __restrict__ nd2,
                                const int* __restrict__ edges,
                                const int* __restrict__ labels,
                                float* __restrict__ part) {
  __shared__ float buf[4];
  const int wave = threadIdx.x >> 6, lane = threadIdx.x & 63;
  const int e = blockIdx.x * 4 + wave;
  const int ni = edges[e * 2], nj = edges[e * 2 + 1];
  const i32x4* hi = (const i32x4*)(H2 + (size_t)ni * N_DIM);
  const i32x4* hj = (const i32x4*)(H2 + (size_t)nj * N_DIM);
  float s12 = 0.f;
#pragma unroll 2
  for (int t = 0; t < 8; ++t) {
    const int idx = lane + t * 64;
    i32x4 a = hi[idx], b = hj[idx];
#pragma unroll
    for (int j = 0; j < 4; ++j) {
      f32x2 al = unpk_lo((u32)a[j]), ah = unpk_hi((u32)a[j]);
      f32x2 bl = unpk_lo((u32)b[j]), bh = unpk_hi((u32)b[j]);
      float d;
      d = al.x - bl.x; s12 += d * d;
      d = al.y - bl.y; s12 += d * d;
      d = ah.x - bh.x; s12 += d * d;
      d = ah.y - bh.y; s12 += d * d;
    }
  }
  s12 = wave_red(s12);
  if (lane == 0) {
    float lab = (labels[e] != 0) ? 1.f : 0.f;
    float fac = (labels[e] != 0) ? PENALTY_F : 1.f;
    buf[wave] = (lab * sqrtf(s12) + fac * (sqrtf(nd2[ni]) + sqrtf(nd2[nj]))) *
                INV_WSCALE;
  }
  __syncthreads();
  if (threadIdx.x == 0)
    atomicAdd(PSLOT(part), buf[0] + buf[1] + buf[2] + buf[3]);
}

// ---------------------------------------------------------------------------
// sum the 64 partial slots into out
// ---------------------------------------------------------------------------
__global__ void finalize_sum(const float* __restrict__ part,
                             float* __restrict__ out) {
  float v = part[threadIdx.x * 16];
  v = wave_red(v);
  if (threadIdx.x == 0) atomicAdd(out, v);
}

// ---------------------------------------------------------------------------
extern "C" void kernel_launch(void* const* d_in, const int* in_sizes, int n_in,
                              void* d_out, int out_size, void* d_ws,
                              size_t ws_size, hipStream_t stream) {
  const float* A = (const float*)d_in[0];
  const float* W1 = (const float*)d_in[1];
  const float* b1 = (const float*)d_in[2];
  const float* W2 = (const float*)d_in[3];
  const float* b2 = (const float*)d_in[4];
  const int* edges = (const int*)d_in[5];
  const int* labels = (const int*)d_in[6];
  float* out = (float*)d_out;

  // workspace layout (bytes), ~152 MB
  char* ws = (char*)d_ws;
  u8* A8   = (u8*)(ws);                       // N x N fp8     64 MB
  u8* H1_8 = (u8*)(ws + 67108864ull);         // N x H fp8      8 MB
  u8* H2_8 = (u8*)(ws + 75497472ull);         // N x N fp8     64 MB
  u8* W1_8 = (u8*)(ws + 142606336ull);        // H x N fp8      8 MB
  u8* W2_8 = (u8*)(ws + 150994944ull);        // N x H fp8      8 MB
  float* nd2  = (float*)(ws + 159383552ull);  // 8192 floats   32 KB
  float* part = (float*)(ws + 159416320ull);  // 64 slots x 64B 4 KB

  hipMemsetAsync(out, 0, sizeof(float), stream);
  hipMemsetAsync(nd2, 0, N_DIM * sizeof(float) + 64 * 16 * sizeof(float),
                 stream);  // zeroes nd2 + part (contiguous)

  // A -> fp8 (scale 1), grid-stride
  convert_f32_fp8<<<2048, 256, 0, stream>>>(A, A8, N_DIM * N_DIM / 4, 1.0f);

  // W1/W2 convert (*16) fused with row norms; b1/b2 norms; all *E, exact fp32
  prep_w<<<H_DIM + N_DIM / 4 + 2, 256, 0, stream>>>(W1, W2, b1, b2, W1_8,
                                                    W2_8, part);

  // layer 1: H1 = sigmoid(A @ W1^T + b1)   [N x H]  128^2 tiles
  gemm_fp8_sigmoid<<<dim3(H_DIM / BN, N_DIM / BM), 256, 0, stream>>>(
      A8, W1_8, b1, H1_8, INV_WSCALE, N_DIM, H_DIM);
  edge_loss_h<<<E_DIM / 4, 256, 0, stream>>>(H1_8, edges, labels, part);

  // layer 2: H2 = sigmoid(H1 @ W2^T + b2)  [N x N]  256^2 2-phase + nd2
  gemm2_fp8_sigmoid<<<dim3(N_DIM / BN2, N_DIM / BM2), 512, 0, stream>>>(
      H1_8, W2_8, b2, H2_8, A8, nd2, INV_WSCALE * INV_WSCALE, H_DIM, N_DIM);
  edge_loss_final<<<E_DIM / 4, 256, 0, stream>>>(H2_8, nd2, edges, labels,
                                                 part);

  finalize_sum<<<1, 64, 0, stream>>>(part, out);
}

// Round 7
// 651.479 us; speedup vs baseline: 1.1176x; 1.0035x over previous
//
#include <hip/hip_runtime.h>
#include <hip/hip_bf16.h>
#include <stdint.h>

#define N_DIM 8192
#define H_DIM 1024
#define E_DIM 8192
#define PENALTY_F 10.0f
#define WSCALE 16.0f      // weights and H outputs stored *16 in e4m3
#define INV_WSCALE 0.0625f

// part-slot layout: [0,3074) prep blocks; [4096,6144) edge_all blocks.
#define PREP_SLOTS 3074
#define EDGE_BASE 4096

typedef unsigned short u16;
typedef unsigned char u8;
typedef unsigned int u32;
typedef __attribute__((ext_vector_type(4))) float f32x4;
typedef __attribute__((ext_vector_type(2))) float f32x2;
typedef __attribute__((ext_vector_type(4))) int i32x4;
typedef __attribute__((ext_vector_type(8))) int i32x8;

// pack 4 floats -> 4 e4m3 bytes (OCP on gfx950)
__device__ __forceinline__ u32 pack4_fp8(float a, float b, float c, float d) {
  u32 p = __builtin_amdgcn_cvt_pk_fp8_f32(a, b, 0, false);
  p = __builtin_amdgcn_cvt_pk_fp8_f32(c, d, p, true);
  return p;
}
__device__ __forceinline__ f32x2 unpk_lo(u32 v) {
  return __builtin_amdgcn_cvt_pk_f32_fp8(v, false);
}
__device__ __forceinline__ f32x2 unpk_hi(u32 v) {
  return __builtin_amdgcn_cvt_pk_f32_fp8(v, true);
}

#define GLD16(ldsptr, gptr)                                                     \
  __builtin_amdgcn_global_load_lds(                                             \
      (__attribute__((address_space(1))) void*)(gptr),                          \
      (__attribute__((address_space(3))) void*)(ldsptr), 16, 0, 0)

// ---------------------------------------------------------------------------
// reduce helpers
// ---------------------------------------------------------------------------
__device__ __forceinline__ float wave_red(float v) {
  for (int o = 32; o; o >>= 1) v += __shfl_down(v, o, 64);
  return v;
}

__device__ __forceinline__ float block_reduce1(float v) {
  __shared__ float buf[4];
  v = wave_red(v);
  int lane = threadIdx.x & 63, w = threadIdx.x >> 6;
  if (lane == 0) buf[w] = v;
  __syncthreads();
  float r = 0.f;
  if (threadIdx.x == 0) r = buf[0] + buf[1] + buf[2] + buf[3];
  return r;  // valid on thread 0
}

// ---------------------------------------------------------------------------
// MERGED prep: W1/W2 convert(*16)+rownorms, b1/b2 norms (unique part slots,
// stores - no atomics/pre-zero), nd2 zeroing, and A fp32->fp8 convert.
// grid = 3074 prep blocks + 1 zero block + 2048 convert blocks = 5123.
// ---------------------------------------------------------------------------
__global__ void prep_all(const float* __restrict__ A,
                         const float* __restrict__ W1,
                         const float* __restrict__ W2,
                         const float* __restrict__ b1,
                         const float* __restrict__ b2, u8* __restrict__ A8,
                         u8* __restrict__ W1_8, u8* __restrict__ W2_8,
                         float* __restrict__ nd2, float* __restrict__ part) {
  const int blk = blockIdx.x;
  if (blk < H_DIM) {  // W1 row: 8192 floats
    const float4* row = (const float4*)(W1 + (size_t)blk * N_DIM);
    u32* orow = (u32*)(W1_8 + (size_t)blk * N_DIM);
    float s = 0.f;
#pragma unroll
    for (int t = 0; t < 8; ++t) {
      int i = threadIdx.x + t * 256;
      float4 v = row[i];
      s += v.x * v.x + v.y * v.y + v.z * v.z + v.w * v.w;
      orow[i] = pack4_fp8(v.x * WSCALE, v.y * WSCALE, v.z * WSCALE,
                          v.w * WSCALE);
    }
    s = block_reduce1(s);
    if (threadIdx.x == 0) part[blk] = sqrtf(s) * (float)E_DIM;
  } else if (blk < H_DIM + N_DIM / 4) {  // W2: 4 rows/block, 1024 floats each
    __shared__ float buf[4];
    const int wave = threadIdx.x >> 6, lane = threadIdx.x & 63;
    const int r = (blk - H_DIM) * 4 + wave;
    const float4* row = (const float4*)(W2 + (size_t)r * H_DIM);
    u32* orow = (u32*)(W2_8 + (size_t)r * H_DIM);
    float s = 0.f;
#pragma unroll
    for (int t = 0; t < 4; ++t) {
      int i = lane + t * 64;
      float4 v = row[i];
      s += v.x * v.x + v.y * v.y + v.z * v.z + v.w * v.w;
      orow[i] = pack4_fp8(v.x * WSCALE, v.y * WSCALE, v.z * WSCALE,
                          v.w * WSCALE);
    }
    s = wave_red(s);
    if (lane == 0) buf[wave] = sqrtf(s);
    __syncthreads();
    if (threadIdx.x == 0)
      part[blk] = (buf[0] + buf[1] + buf[2] + buf[3]) * (float)E_DIM;
  } else if (blk == H_DIM + N_DIM / 4) {  // ||b1||
    const float4* row = (const float4*)b1;
    float4 v = row[threadIdx.x];
    float s = v.x * v.x + v.y * v.y + v.z * v.z + v.w * v.w;
    s = block_reduce1(s);
    if (threadIdx.x == 0) part[blk] = sqrtf(s) * (float)E_DIM;
  } else if (blk == H_DIM + N_DIM / 4 + 1) {  // ||b2||
    const float4* row = (const float4*)b2;
    float s = 0.f;
#pragma unroll
    for (int t = 0; t < 8; ++t) {
      float4 v = row[threadIdx.x + t * 256];
      s += v.x * v.x + v.y * v.y + v.z * v.z + v.w * v.w;
    }
    s = block_reduce1(s);
    if (threadIdx.x == 0) part[blk] = sqrtf(s) * (float)E_DIM;
  } else if (blk == PREP_SLOTS) {  // zero nd2 (needed before GEMM2 atomics)
    f32x4 z = {0.f, 0.f, 0.f, 0.f};
#pragma unroll
    for (int t = 0; t < 8; ++t)
      ((f32x4*)nd2)[threadIdx.x + t * 256] = z;
  } else {  // A -> fp8, grid-stride over 2048 blocks
    const int cb = blk - (PREP_SLOTS + 1);
    const int n4 = N_DIM * N_DIM / 4;
    for (int i = cb * 256 + threadIdx.x; i < n4; i += 2048 * 256) {
      float4 v = ((const float4*)A)[i];
      ((u32*)A8)[i] = pack4_fp8(v.x, v.y, v.z, v.w);
    }
  }
}

// ---------------------------------------------------------------------------
// GEMM1: 128x128 tile, verified 2-barrier structure, XCD-aware remap.
// C = fp8( WSCALE * sigmoid( invScale*(A B^T) + bias ) ), swapped MFMA.
// ---------------------------------------------------------------------------
#define BM 128
#define BN 128
#define BKB 128

__global__ __launch_bounds__(256) void gemm_fp8_sigmoid(
    const u8* __restrict__ Ag,    // [M][K]
    const u8* __restrict__ Bg,    // [Nd][K]
    const float* __restrict__ bias,
    u8* __restrict__ Cg,          // [M][Nd] e4m3, value*WSCALE
    float invScale, int K, int Nd) {
  __shared__ __align__(16) u8 Xs[BM * BKB];
  __shared__ __align__(16) u8 Ws[BN * BKB];

  // bijective XCD remap: XCD k gets contiguous chunk of flat ids (nwg%8==0)
  const int nwg = gridDim.x * gridDim.y;
  const int id = blockIdx.y * gridDim.x + blockIdx.x;
  const int wg = (id & 7) * (nwg >> 3) + (id >> 3);
  const int bx = wg % gridDim.x;
  const int by = wg / gridDim.x;

  const int tid = threadIdx.x;
  const int wave = tid >> 6, lane = tid & 63;
  const int wr = wave >> 1, wc = wave & 1;
  const size_t rowBase = (size_t)by * BM;
  const size_t colBase = (size_t)bx * BN;

  f32x4 acc[4][4] = {};

  const int i8 = lane >> 3;  // row within 8-row staging group
  const int c8 = lane & 7;   // LDS 16-B slot
  const int sw = c8 ^ i8;    // swizzled global 16-B unit

  const int quad = lane >> 4;
  const int m15 = lane & 15;

  for (int k0 = 0; k0 < K; k0 += BKB) {
#pragma unroll
    for (int j = 0; j < 4; ++j) {
      const int r0 = (wave * 4 + j) * 8;
      const u8* gx = Ag + (rowBase + r0 + i8) * (size_t)K + (k0 + sw * 16);
      GLD16(&Xs[r0 * BKB], gx);
      const u8* gw = Bg + (colBase + r0 + i8) * (size_t)K + (k0 + sw * 16);
      GLD16(&Ws[r0 * BKB], gw);
    }
    __syncthreads();

    i32x8 af[4], bfr[4];
#pragma unroll
    for (int t = 0; t < 4; ++t) {
      const int m = wr * 64 + t * 16 + m15;
      i32x4 alo = *(const i32x4*)&Xs[m * BKB + ((2 * quad) ^ (m & 7)) * 16];
      i32x4 ahi = *(const i32x4*)&Xs[m * BKB + ((2 * quad + 1) ^ (m & 7)) * 16];
      af[t] = __builtin_shufflevector(alo, ahi, 0, 1, 2, 3, 4, 5, 6, 7);
      const int n = wc * 64 + t * 16 + m15;
      i32x4 blo = *(const i32x4*)&Ws[n * BKB + ((2 * quad) ^ (n & 7)) * 16];
      i32x4 bhi = *(const i32x4*)&Ws[n * BKB + ((2 * quad + 1) ^ (n & 7)) * 16];
      bfr[t] = __builtin_shufflevector(blo, bhi, 0, 1, 2, 3, 4, 5, 6, 7);
    }
#pragma unroll
    for (int mt = 0; mt < 4; ++mt)
#pragma unroll
      for (int nt = 0; nt < 4; ++nt)
        acc[mt][nt] = __builtin_amdgcn_mfma_scale_f32_16x16x128_f8f6f4(
            bfr[nt], af[mt], acc[mt][nt], 0, 0,
            0, 0x7F7F7F7F, 0, 0x7F7F7F7F);  // SWAPPED: D[n][m] layout
    __syncthreads();
  }

  // epilogue: lane owns C row (mt*16+m15), cols nt*16+quad*4+{0..3}
  f32x4 bv4[4];
#pragma unroll
  for (int nt = 0; nt < 4; ++nt)
    bv4[nt] = *(const f32x4*)&bias[colBase + wc * 64 + nt * 16 + quad * 4];
#pragma unroll
  for (int mt = 0; mt < 4; ++mt) {
    const size_t grow = rowBase + wr * 64 + mt * 16 + m15;
    u32* crow = (u32*)(Cg + grow * (size_t)Nd + colBase + wc * 64);
#pragma unroll
    for (int nt = 0; nt < 4; ++nt) {
      float v[4];
#pragma unroll
      for (int i = 0; i < 4; ++i) {
        float x = acc[mt][nt][i] * invScale + bv4[nt][i];
        v[i] = WSCALE / (1.0f + __expf(-x));
      }
      crow[nt * 4 + quad] = pack4_fp8(v[0], v[1], v[2], v[3]);
    }
  }
}

// ---------------------------------------------------------------------------
// GEMM2: 256x256 tile, 8 waves (2x4), double-buffered LDS (128 KB), 1 blk/CU.
// 2-phase pipeline + T5 setprio. Epilogue also accumulates
// nd2[row] = sum_cols (WSCALE*A8[row][c] - H2q[row][c])^2 (quantized H2 ->
// bit-identical to a re-read), with quad-level shfl pre-reduce so only
// lane<16 issues the LDS atomic (4-way collision instead of 16-way).
// ---------------------------------------------------------------------------
#define BM2 256
#define BN2 256

__global__ __launch_bounds__(512, 2) void gemm2_fp8_sigmoid(
    const u8* __restrict__ Ag,    // [M][K]  (H1)
    const u8* __restrict__ Bg,    // [Nd][K] (W2)
    const float* __restrict__ bias,
    u8* __restrict__ Cg,          // [M][Nd] e4m3, value*WSCALE
    const u8* __restrict__ A8,    // [M][Nd] e4m3 (X, scale 1)
    float* __restrict__ nd2,      // [M] per-node sum of squares (pre-zeroed)
    float invScale, int K, int Nd) {
  __shared__ __align__(16) u8 Xs[2][BM2 * BKB];   // 2 x 32 KB
  __shared__ __align__(16) u8 Ws[2][BN2 * BKB];   // 2 x 32 KB

  const int tid = threadIdx.x;
  const int wave = tid >> 6, lane = tid & 63;
  const int wr = wave >> 2;          // 0..1 -> 128-row half
  const int wc = wave & 3;           // 0..3 -> 64-col quarter
  const size_t rowBase = (size_t)blockIdx.y * BM2;
  const size_t colBase = (size_t)blockIdx.x * BN2;

  f32x4 acc[8][4] = {};

  const int i8 = lane >> 3;
  const int c8 = lane & 7;
  const int sw = c8 ^ i8;            // swizzled global 16-B unit (key: row&7)
  const int quad = lane >> 4;
  const int m15 = lane & 15;

  const int T = K / BKB;

  auto STAGE = [&](int kt, int b) {
    const size_t kOff = (size_t)kt * BKB + sw * 16;
#pragma unroll
    for (int j = 0; j < 4; ++j) {
      const int r0 = (wave * 4 + j) * 8;  // 8 waves * 4 * 8 = 256 rows
      GLD16(&Xs[b][r0 * BKB], Ag + (rowBase + r0 + i8) * (size_t)K + kOff);
      GLD16(&Ws[b][r0 * BKB], Bg + (colBase + r0 + i8) * (size_t)K + kOff);
    }
  };

  STAGE(0, 0);
  __syncthreads();

  for (int t = 0; t < T; ++t) {
    const int cur = t & 1;
    if (t + 1 < T) STAGE(t + 1, cur ^ 1);  // in flight across this tile's MFMA

    const u8* Xb = Xs[cur];
    const u8* Wb = Ws[cur];

    i32x8 bfr[4];
#pragma unroll
    for (int nt = 0; nt < 4; ++nt) {
      const int n = wc * 64 + nt * 16 + m15;
      i32x4 blo = *(const i32x4*)&Wb[n * BKB + ((2 * quad) ^ (n & 7)) * 16];
      i32x4 bhi = *(const i32x4*)&Wb[n * BKB + ((2 * quad + 1) ^ (n & 7)) * 16];
      bfr[nt] = __builtin_shufflevector(blo, bhi, 0, 1, 2, 3, 4, 5, 6, 7);
    }
    __builtin_amdgcn_s_setprio(1);
#pragma unroll
    for (int mt = 0; mt < 8; ++mt) {
      const int m = wr * 128 + mt * 16 + m15;
      i32x4 alo = *(const i32x4*)&Xb[m * BKB + ((2 * quad) ^ (m & 7)) * 16];
      i32x4 ahi = *(const i32x4*)&Xb[m * BKB + ((2 * quad + 1) ^ (m & 7)) * 16];
      i32x8 af = __builtin_shufflevector(alo, ahi, 0, 1, 2, 3, 4, 5, 6, 7);
#pragma unroll
      for (int nt = 0; nt < 4; ++nt)
        acc[mt][nt] = __builtin_amdgcn_mfma_scale_f32_16x16x128_f8f6f4(
            bfr[nt], af, acc[mt][nt], 0, 0,
            0, 0x7F7F7F7F, 0, 0x7F7F7F7F);  // SWAPPED: lane owns C-row m
    }
    __builtin_amdgcn_s_setprio(0);
    __syncthreads();  // drains this wave's t+1 loads + fences buf reuse
  }

  // ---- epilogue: store H2 fp8 + accumulate nd2 per row ----
  // K-loop's trailing __syncthreads => LDS free; overlay Xs with ndbuf[256].
  float* ndbuf = (float*)&Xs[0][0];
  if (tid < 256) ndbuf[tid] = 0.f;
  __syncthreads();

  f32x4 bv4[4];
#pragma unroll
  for (int nt = 0; nt < 4; ++nt)
    bv4[nt] = *(const f32x4*)&bias[colBase + wc * 64 + nt * 16 + quad * 4];
#pragma unroll
  for (int mt = 0; mt < 8; ++mt) {
    const int rowLocal = wr * 128 + mt * 16 + m15;  // 0..255
    const size_t grow = rowBase + rowLocal;
    u32* crow = (u32*)(Cg + grow * (size_t)Nd + colBase + wc * 64);
    const u32* arow = (const u32*)(A8 + grow * (size_t)Nd + colBase + wc * 64);
    float nds = 0.f;
#pragma unroll
    for (int nt = 0; nt < 4; ++nt) {
      float v[4];
#pragma unroll
      for (int i = 0; i < 4; ++i) {
        float x = acc[mt][nt][i] * invScale + bv4[nt][i];
        v[i] = WSCALE / (1.0f + __expf(-x));
      }
      const u32 packed = pack4_fp8(v[0], v[1], v[2], v[3]);
      crow[nt * 4 + quad] = packed;
      // quantized H2 values (exactly what a re-read would give)
      f32x2 hlo = unpk_lo(packed), hhi = unpk_hi(packed);
      const u32 xa = arow[nt * 4 + quad];
      f32x2 xlo = unpk_lo(xa), xhi = unpk_hi(xa);
      float d;
      d = WSCALE * xlo.x - hlo.x; nds += d * d;
      d = WSCALE * xlo.y - hlo.y; nds += d * d;
      d = WSCALE * xhi.x - hhi.x; nds += d * d;
      d = WSCALE * xhi.y - hhi.y; nds += d * d;
    }
    // reduce across the 4 quads in-wave; lanes 0..15 hold the per-row sum
    nds += __shfl_down(nds, 32, 64);
    nds += __shfl_down(nds, 16, 64);
    if (lane < 16) atomicAdd(&ndbuf[rowLocal], nds);  // 4 wc-waves collide
  }
  __syncthreads();
  if (tid < 256) atomicAdd(&nd2[rowBase + tid], ndbuf[tid]);
}

// ---------------------------------------------------------------------------
// merged edge loss: one WAVE per edge (4 edges/block).
//   labeled:  lab*(||H1i-H1j|| + ||H2i-H2j||)  (heavy gathers, ~50% of waves)
//   all:      fac*(sqrt(nd2[ni]) + sqrt(nd2[nj]))  (scalars from GEMM2 epi)
// Unique part-slot store per block (no atomics / pre-zero).
// ---------------------------------------------------------------------------
__global__ void edge_all(const u8* __restrict__ H1, const u8* __restrict__ H2,
                         const float* __restrict__ nd2,
                         const int* __restrict__ edges,
                         const int* __restrict__ labels,
                         float* __restrict__ part) {
  __shared__ float buf[4];
  const int wave = threadIdx.x >> 6, lane = threadIdx.x & 63;
  const int e = blockIdx.x * 4 + wave;
  const int ni = edges[e * 2], nj = edges[e * 2 + 1];
  const int lab = labels[e];
  float r = 0.f;
  if (lab != 0) {
    // layer-1 term: H_DIM=1024 fp8 -> one i32x4 per lane
    const i32x4 a1 = ((const i32x4*)(H1 + (size_t)ni * H_DIM))[lane];
    const i32x4 b1v = ((const i32x4*)(H1 + (size_t)nj * H_DIM))[lane];
    float s1 = 0.f;
#pragma unroll
    for (int j = 0; j < 4; ++j) {
      f32x2 al = unpk_lo((u32)a1[j]), ah = unpk_hi((u32)a1[j]);
      f32x2 bl = unpk_lo((u32)b1v[j]), bh = unpk_hi((u32)b1v[j]);
      float d0 = al.x - bl.x, d1 = al.y - bl.y;
      float d2 = ah.x - bh.x, d3 = ah.y - bh.y;
      s1 += d0 * d0 + d1 * d1 + d2 * d2 + d3 * d3;
    }
    // layer-2 pairwise term: N_DIM=8192 fp8 -> 8 i32x4 per lane per row
    const i32x4* hi = (const i32x4*)(H2 + (size_t)ni * N_DIM);
    const i32x4* hj = (const i32x4*)(H2 + (size_t)nj * N_DIM);
    float s12 = 0.f;
#pragma unroll 2
    for (int t = 0; t < 8; ++t) {
      const int idx = lane + t * 64;
      i32x4 a = hi[idx], b = hj[idx];
#pragma unroll
      for (int j = 0; j < 4; ++j) {
        f32x2 al = unpk_lo((u32)a[j]), ah = unpk_hi((u32)a[j]);
        f32x2 bl = unpk_lo((u32)b[j]), bh = unpk_hi((u32)b[j]);
        float d;
        d = al.x - bl.x; s12 += d * d;
        d = al.y - bl.y; s12 += d * d;
        d = ah.x - bh.x; s12 += d * d;
        d = ah.y - bh.y; s12 += d * d;
      }
    }
    for (int o = 32; o; o >>= 1) {
      s1 += __shfl_down(s1, o, 64);
      s12 += __shfl_down(s12, o, 64);
    }
    r = (sqrtf(s1) + sqrtf(s12)) * INV_WSCALE;
  }
  if (lane == 0) {
    const float fac = (lab != 0) ? PENALTY_F : 1.f;
    r += fac * (sqrtf(nd2[ni]) + sqrtf(nd2[nj])) * INV_WSCALE;
    buf[wave] = r;
  }
  __syncthreads();
  if (threadIdx.x == 0)
    part[EDGE_BASE + blockIdx.x] = buf[0] + buf[1] + buf[2] + buf[3];
}

// ---------------------------------------------------------------------------
// finalize: sum defined part ranges, STORE to out (no memset needed)
// ---------------------------------------------------------------------------
__global__ void finalize_sum(const float* __restrict__ part,
                             float* __restrict__ out) {
  float s = 0.f;
  for (int i = threadIdx.x; i < PREP_SLOTS; i += 256) s += part[i];
  for (int i = EDGE_BASE + threadIdx.x; i < EDGE_BASE + E_DIM / 4; i += 256)
    s += part[i];
  s = block_reduce1(s);
  if (threadIdx.x == 0) *out = s;
}

// ---------------------------------------------------------------------------
extern "C" void kernel_launch(void* const* d_in, const int* in_sizes, int n_in,
                              void* d_out, int out_size, void* d_ws,
                              size_t ws_size, hipStream_t stream) {
  const float* A = (const float*)d_in[0];
  const float* W1 = (const float*)d_in[1];
  const float* b1 = (const float*)d_in[2];
  const float* W2 = (const float*)d_in[3];
  const float* b2 = (const float*)d_in[4];
  const int* edges = (const int*)d_in[5];
  const int* labels = (const int*)d_in[6];
  float* out = (float*)d_out;

  // workspace layout (bytes), ~152 MB
  char* ws = (char*)d_ws;
  u8* A8   = (u8*)(ws);                       // N x N fp8     64 MB
  u8* H1_8 = (u8*)(ws + 67108864ull);         // N x H fp8      8 MB
  u8* H2_8 = (u8*)(ws + 75497472ull);         // N x N fp8     64 MB
  u8* W1_8 = (u8*)(ws + 142606336ull);        // H x N fp8      8 MB
  u8* W2_8 = (u8*)(ws + 150994944ull);        // N x H fp8      8 MB
  float* nd2  = (float*)(ws + 159383552ull);  // 8192 floats   32 KB
  float* part = (float*)(ws + 159416320ull);  // 6144 floats   24 KB

  // 1: all prep (W convert+norms, b norms, nd2 zero, A convert) in one grid
  prep_all<<<PREP_SLOTS + 1 + 2048, 256, 0, stream>>>(A, W1, W2, b1, b2, A8,
                                                      W1_8, W2_8, nd2, part);

  // 2: H1 = sigmoid(A @ W1^T + b1)   [N x H]  128^2 tiles
  gemm_fp8_sigmoid<<<dim3(H_DIM / BN, N_DIM / BM), 256, 0, stream>>>(
      A8, W1_8, b1, H1_8, INV_WSCALE, N_DIM, H_DIM);

  // 3: H2 = sigmoid(H1 @ W2^T + b2)  [N x N]  256^2 2-phase + nd2 fusion
  gemm2_fp8_sigmoid<<<dim3(N_DIM / BN2, N_DIM / BM2), 512, 0, stream>>>(
      H1_8, W2_8, b2, H2_8, A8, nd2, INV_WSCALE * INV_WSCALE, H_DIM, N_DIM);

  // 4: all edge terms (H1 + H2 pairwise gated by label; nd2 scalars always)
  edge_all<<<E_DIM / 4, 256, 0, stream>>>(H1_8, H2_8, nd2, edges, labels,
                                          part);

  // 5: final reduce, direct store
  finalize_sum<<<1, 256, 0, stream>>>(part, out);
}